// Round 2
// baseline (159.924 us; speedup 1.0000x reference)
//
#include <hip/hip_runtime.h>

constexpr int NRAYS = 131072;
constexpr float DELTA_INF_F = 1e10f;
constexpr float EPS_F = 1e-10f;

// One 64-lane wave per ray; lane l owns samples [3l, 3l+2]. 4 rays/block.
__global__ __launch_bounds__(256) void nerf_render_kernel(
    const float4* __restrict__ rsF4,    // [N*144] positions as float4
    const float4* __restrict__ denF4,   // [N*48]
    const float4* __restrict__ rgbF4,   // [N*144]
    const float* __restrict__ bg,       // [3]
    float* __restrict__ out_rgb,        // [N,3]
    float* __restrict__ out_acc,        // [N]
    float4* __restrict__ out_wF4)       // [N*48]
{
    __shared__ float pos[4][576];
    __shared__ float den[4][192];
    __shared__ float wbuf[4][192];

    const int lane = threadIdx.x & 63;
    const int w    = threadIdx.x >> 6;
    const int ray  = (blockIdx.x << 2) + w;

    // ---- issue all global loads up front, fully coalesced float4 ----
    const float4* rg = rgbF4 + (size_t)ray * 144;
    float4 c0 = rg[lane];
    float4 c1 = rg[lane + 64];
    float4 c2 = make_float4(0.f, 0.f, 0.f, 0.f);
    if (lane < 16) c2 = rg[lane + 128];

    const float4* rp = rsF4 + (size_t)ray * 144;
    float4 p0 = rp[lane];
    float4 p1 = rp[lane + 64];
    float4 p2 = make_float4(0.f, 0.f, 0.f, 0.f);
    if (lane < 16) p2 = rp[lane + 128];

    float4 dd = make_float4(0.f, 0.f, 0.f, 0.f);
    if (lane < 48) dd = denF4[(size_t)ray * 48 + lane];

    // ---- stage positions + densities to LDS (contiguous b128, conflict-free) ----
    float4* pl = (float4*)&pos[w][0];
    pl[lane]      = p0;
    pl[lane + 64] = p1;
    if (lane < 16) pl[lane + 128] = p2;
    if (lane < 48) ((float4*)&den[w][0])[lane] = dd;

    __syncthreads();

    // ---- per-lane: samples 3l..3l+2 ----
    const int pb = 9 * lane;
    float q0x = pos[w][pb+0], q0y = pos[w][pb+1], q0z = pos[w][pb+2];
    float q1x = pos[w][pb+3], q1y = pos[w][pb+4], q1z = pos[w][pb+5];
    float q2x = pos[w][pb+6], q2y = pos[w][pb+7], q2z = pos[w][pb+8];

    float dx = q1x - q0x, dy = q1y - q0y, dz = q1z - q0z;
    float d0 = sqrtf(dx*dx + dy*dy + dz*dz);
    dx = q2x - q1x; dy = q2y - q1y; dz = q2z - q1z;
    float d1 = sqrtf(dx*dx + dy*dy + dz*dz);
    float d2 = DELTA_INF_F;
    if (lane < 63) {
        float nx = pos[w][pb+9], ny = pos[w][pb+10], nz = pos[w][pb+11];
        dx = nx - q2x; dy = ny - q2y; dz = nz - q2z;
        d2 = sqrtf(dx*dx + dy*dy + dz*dz);
    }

    float s0 = den[w][3*lane+0], s1 = den[w][3*lane+1], s2 = den[w][3*lane+2];
    float e0 = expf(-fmaxf(s0, 0.f) * d0);
    float e1 = expf(-fmaxf(s1, 0.f) * d1);
    float e2 = expf(-fmaxf(s2, 0.f) * d2);

    float a0 = 1.f - e0, a1 = 1.f - e1, a2 = 1.f - e2;
    float t0 = (1.f - a0) + EPS_F;
    float t1 = (1.f - a1) + EPS_F;
    float t2 = (1.f - a2) + EPS_F;

    // ---- exclusive cumprod across lanes ----
    float incl = t0 * t1 * t2;
#pragma unroll
    for (int off = 1; off < 64; off <<= 1) {
        float t = __shfl_up(incl, off);
        if (lane >= off) incl *= t;
    }
    float pref = __shfl_up(incl, 1);
    if (lane == 0) pref = 1.f;

    float w0 = a0 * pref;
    float w1 = a1 * pref * t0;
    float w2 = a2 * pref * t0 * t1;
    float acc = w0 + w1 + w2;

    wbuf[w][3*lane+0] = w0;
    wbuf[w][3*lane+1] = w1;
    wbuf[w][3*lane+2] = w2;

    __syncthreads();

    // ---- coalesced weight store ----
    if (lane < 48)
        out_wF4[(size_t)ray * 48 + lane] = ((const float4*)&wbuf[w][0])[lane];

    // ---- weighted rgb: per-lane 12 elements, channel-grouped by (j+k)%3 ----
    float a_0 = 0.f, a_1 = 0.f, a_2 = 0.f;   // a[(j+k)%3]
    {
        const float* cv0 = &c0.x;
        const float* cv1 = &c1.x;
        const float* cv2 = &c2.x;
#pragma unroll
        for (int j = 0; j < 4; ++j) {
            // k=0: widx = l + (l+j)/3, group (j+0)%3
            float m0 = cv0[j] * wbuf[w][lane + (lane + j) / 3];
            if ((j + 0) % 3 == 0) a_0 += m0; else if ((j + 0) % 3 == 1) a_1 += m0; else a_2 += m0;
            // k=1: widx = l + 85 + (l+j+1)/3, group (j+1)%3
            float m1 = cv1[j] * wbuf[w][lane + 85 + (lane + j + 1) / 3];
            if ((j + 1) % 3 == 0) a_0 += m1; else if ((j + 1) % 3 == 1) a_1 += m1; else a_2 += m1;
            // k=2 (lanes<16): widx = l + 170 + (l+j+2)/3, group (j+2)%3
            if (lane < 16) {
                float m2 = cv2[j] * wbuf[w][lane + 170 + (lane + j + 2) / 3];
                if ((j + 2) % 3 == 0) a_0 += m2; else if ((j + 2) % 3 == 1) a_1 += m2; else a_2 += m2;
            }
        }
    }
    // group i holds channel (b + i) % 3, b = lane % 3  ->  rotate
    const int b = lane % 3;
    float cr = (b == 0) ? a_0 : ((b == 1) ? a_2 : a_1);
    float cg = (b == 0) ? a_1 : ((b == 1) ? a_0 : a_2);
    float cb = (b == 0) ? a_2 : ((b == 1) ? a_1 : a_0);

#pragma unroll
    for (int off = 32; off >= 1; off >>= 1) {
        cr  += __shfl_xor(cr, off);
        cg  += __shfl_xor(cg, off);
        cb  += __shfl_xor(cb, off);
        acc += __shfl_xor(acc, off);
    }

    if (lane == 0) {
        float om = 1.f - acc;
        out_rgb[(size_t)ray*3 + 0] = cr + bg[0] * om;
        out_rgb[(size_t)ray*3 + 1] = cg + bg[1] * om;
        out_rgb[(size_t)ray*3 + 2] = cb + bg[2] * om;
        out_acc[ray] = acc;
    }
}

extern "C" void kernel_launch(void* const* d_in, const int* in_sizes, int n_in,
                              void* d_out, int out_size, void* d_ws, size_t ws_size,
                              hipStream_t stream) {
    const float4* rsF4  = (const float4*)d_in[0];
    const float4* denF4 = (const float4*)d_in[1];
    const float4* rgbF4 = (const float4*)d_in[2];
    const float*  bg    = (const float*)d_in[3];

    float* o = (float*)d_out;
    float*  out_rgb = o;                                  // N*3
    float*  out_acc = o + (size_t)NRAYS * 3;              // N
    float4* out_wF4 = (float4*)(o + (size_t)NRAYS * 4);   // N*192

    dim3 grid(NRAYS / 4), block(256);
    hipLaunchKernelGGL(nerf_render_kernel, grid, block, 0, stream,
                       rsF4, denF4, rgbF4, bg, out_rgb, out_acc, out_wF4);
}